// Round 10
// baseline (65.555 us; speedup 1.0000x reference)
//
#include <hip/hip_runtime.h>

#define BIGF 1e10f
#define HH 256
#define WW 256
#define BB 4
#define NPIX (BB * HH * WW)
#define GRID 256            // == #CUs: 1 block/CU (launch_bounds 1024,4 => co-resident)
#define MAGIC 0x5F3A9C71u   // multi-byte value: cannot alias a byte-pattern ws poison
#define SMAX 3              // local column window; exact iff best <= (SMAX+1)^2
#define CONV_T 16.0f        // (SMAX+1)^2

// ws layout (bytes):
//   [0 .. 2047]     u64 accb[256] : per-block double partial sums (bit pattern)
//   [2048 .. 2051]  u32 cnt  : finish ticket counter (init by blk0 at entry)
//   [2112 .. 2115]  u32 initf: cnt-initialized gate (MAGIC)
// accb needs no init (read only after ticket 255, each store ACKed pre-ticket).
#define WS_ACCB_OFF 0
#define WS_CNT_OFF 2048
#define WS_INIT_OFF 2112

#define LOAD_RLX(p)     __hip_atomic_load((p), __ATOMIC_RELAXED, __HIP_MEMORY_SCOPE_AGENT)
#define STORE_RLX(p, v) __hip_atomic_store((p), (v), __ATOMIC_RELAXED, __HIP_MEMORY_SCOPE_AGENT)

// Exact 1D distance^2 along a row to the nearest bit of class (mask ^ iv),
// from position x. 8 u32 words per row in LDS; near-uniform addresses per wave.
__device__ inline float row_d2(const unsigned* __restrict__ rm, int x, unsigned iv) {
    int wx = x >> 5, bx = x & 31;
    int dl = 1 << 20, dr = 1 << 20;
    unsigned m0 = rm[wx] ^ iv;                    // shared by both directions
    unsigned t = m0 & (0xFFFFFFFFu >> (31 - bx)); // bits <= bx
    int w = wx;
    while (true) {
        if (t) { int p = (w << 5) + 31 - __builtin_clz(t); dl = x - p; break; }
        if (--w < 0) break;
        t = rm[w] ^ iv;
    }
    t = m0 & (0xFFFFFFFFu << bx);                 // bits >= bx
    w = wx;
    while (true) {
        if (t) { int p = (w << 5) + __builtin_ctz(t); dr = p - x; break; }
        if (++w > 7) break;
        t = rm[w] ^ iv;
    }
    int d = dl < dr ? dl : dr;
    return (d > 255) ? BIGF : (float)(d * d);
}

// Exact expanding-window min-plus along the column (full range, fallback path).
__device__ inline float col_min(const unsigned* __restrict__ mb, int y, int x, unsigned iv) {
    float best = row_d2(mb + y * 8, x, iv);
    #pragma unroll 1
    for (int s = 1; s < HH; ++s) {
        float ss = (float)(s * s);
        if (ss >= best) break;
        int ym = y - s, yp = y + s;
        if (ym >= 0) best = fminf(best, row_d2(mb + ym * 8, x, iv) + ss);
        if (yp < HH) best = fminf(best, row_d2(mb + yp * 8, x, iv) + ss);
    }
    return best;
}

// Fused truncated variant: both images in ONE s-loop (2x ILP on the dependent
// LDS-scan chain). Per-image iterations are identical to the full loop while
// s <= SMAX; result exact iff it converged (best <= (SMAX+1)^2: any s>SMAX
// candidate costs >= that, and the full loop breaks on ss >= best).
__device__ inline void col_min2_win(const unsigned* __restrict__ mb0,
                                    const unsigned* __restrict__ mb1,
                                    int y, int x, unsigned iv0, unsigned iv1,
                                    float& b0, float& b1) {
    b0 = row_d2(mb0 + y * 8, x, iv0);
    b1 = row_d2(mb1 + y * 8, x, iv1);
    #pragma unroll 1
    for (int s = 1; s <= SMAX; ++s) {
        float ss = (float)(s * s);
        bool d0 = (ss >= b0), d1 = (ss >= b1);
        if (d0 && d1) break;
        int ym = y - s, yp = y + s;
        if (!d0) {
            if (ym >= 0) b0 = fminf(b0, row_d2(mb0 + ym * 8, x, iv0) + ss);
            if (yp < HH) b0 = fminf(b0, row_d2(mb0 + yp * 8, x, iv0) + ss);
        }
        if (!d1) {
            if (ym >= 0) b1 = fminf(b1, row_d2(mb1 + ym * 8, x, iv1) + ss);
            if (yp < HH) b1 = fminf(b1, row_d2(mb1 + yp * 8, x, iv1) + ss);
        }
    }
}

// pack one row's 256 pixels into 8 mask words: float4/lane + nibble + shfl OR-tree
#define PACK_ROW(rowp, vout)                                                  \
    {                                                                         \
        const float4 f = ((const float4*)(rowp))[lane];                       \
        unsigned nib = (f.x > 0.5f ? 1u : 0u) | (f.y > 0.5f ? 2u : 0u)        \
                     | (f.z > 0.5f ? 4u : 0u) | (f.w > 0.5f ? 8u : 0u);       \
        vout = nib << ((lane & 7) << 2);                                      \
        vout |= __shfl_xor(vout, 1, 64);                                      \
        vout |= __shfl_xor(vout, 2, 64);                                      \
        vout |= __shfl_xor(vout, 4, 64);                                      \
    }

// Self-sufficient kernel, ticket tail: fast path = local +-SMAX window build +
// fused truncated col_min (exact when converged; convergence implies fg-any).
// Rare fallback: local FULL 512-row rebuild + exact col_min with fg-any gates.
// Tail: publish partial (sc1+ACK) -> device atomicAdd ticket -> LAST finisher
// (already hot) reduces all 256 partials and writes out. No idle block-0 spin,
// no flag-poll pickup hop. cnt gated by entry-raised init-MAGIC (poison-safe).
__launch_bounds__(1024, 4)
__global__ void hdt_kernel(const float* __restrict__ pred,
                           const float* __restrict__ tgt,
                           unsigned* __restrict__ cnt,
                           unsigned* __restrict__ initf,
                           unsigned long long* __restrict__ accb,
                           float* __restrict__ out) {
    // XCD-aware swizzle: blockIdx round-robins XCDs; chunk so logical tiles
    // 0..31 land on XCD0, etc. Speed-only (L2 locality), not correctness.
    int blk = ((blockIdx.x & 7) << 5) | (blockIdx.x >> 3);
    int b = blk >> 6;
    int tid = threadIdx.x;
    int w = tid >> 6, lane = tid & 63;

    __shared__ __align__(16) unsigned lmask[2][HH][8];   // 16 KB (full, for fallback)
    __shared__ unsigned wfl[16];
    __shared__ float wsum[16];
    __shared__ double dsum[4];
    __shared__ unsigned lastFlag;

    // ---- Entry init (blk 0 only, BEFORE any VM reads so the ACK is instant):
    // zero the ticket counter, then raise the gate. Raised ~entry; every
    // consumer polls it only at the very end => one-shot hit in practice.
    if (blk == 0 && tid == 0) {
        STORE_RLX(cnt, 0u);
        asm volatile("s_waitcnt vmcnt(0)" ::: "memory");  // zero ACKed at coherence pt
        STORE_RLX(initf, MAGIC);
    }

    // prefetch this thread's query pixels: latency hides under the build
    int x = tid & (WW - 1);
    int y0 = (blk & 63) << 2;
    int yq = y0 + (tid >> 8);                 // wave-uniform row of the 4-row tile
    int idx = (b * HH + yq) * WW + x;
    float pv = pred[idx], tv = tgt[idx];

    // ---- Local window build: rows [y0-SMAX, y0+3+SMAX] clamped, both images.
    // <= 20 row-builds: waves 0-3 do 2, waves 4-15 do 1.
    int ylo = y0 - SMAX; if (ylo < 0) ylo = 0;
    int yhi = y0 + 3 + SMAX; if (yhi > HH - 1) yhi = HH - 1;
    int nrows = yhi - ylo + 1;
    int tot = nrows * 2;
    #pragma unroll 2
    for (int i = w; i < tot; i += 16) {
        int img = (i >= nrows) ? 1 : 0;
        int y = ylo + (img ? i - nrows : i);
        const float* rowp = (img ? tgt : pred) + (b * HH + y) * WW;
        unsigned v;
        PACK_ROW(rowp, v);
        if ((lane & 7) == 0) lmask[img][y][lane >> 3] = v;
    }
    __syncthreads();

    // ---- Fast path: fused truncated col_min on the local window.
    unsigned ivp = (pv > 0.5f) ? 0xFFFFFFFFu : 0u;
    unsigned ivt = (tv > 0.5f) ? 0xFFFFFFFFu : 0u;
    float bp, bt;
    col_min2_win(&lmask[0][0][0], &lmask[1][0][0], yq, x, ivp, ivt, bp, bt);
    bool conv_p = (bp <= CONV_T), conv_t = (bt <= CONV_T);
    float d2p = 0.0f, d2t = 0.0f;
    // converged => bp,bt <= 16 << BIGF: fminf elided; sqrt->square kept to
    // match the reference's f32 rounding exactly.
    if (conv_p) { float dt = sqrtf(bp); d2p = dt * dt; }
    if (conv_t) { float dt = sqrtf(bt); d2t = dt * dt; }

    float e = pv - tv;
    float errsq = e * e;
    float lsum = errsq * (d2p + d2t);

    // ---- Single-barrier ballot + reduce: wave64 shuffle reduce, then wsum[w]
    // and the fallback flag wfl[w] published in the same LDS round trip.
    unsigned long long fb = __ballot(!(conv_p && conv_t));
    #pragma unroll
    for (int off = 32; off > 0; off >>= 1)
        lsum += __shfl_down(lsum, off, 64);
    if (lane == 0) { wsum[w] = lsum; wfl[w] = (fb != 0ULL) ? 1u : 0u; }
    __syncthreads();
    unsigned fb_any = wfl[0] | wfl[1] | wfl[2] | wfl[3] | wfl[4] | wfl[5] | wfl[6]
                    | wfl[7] | wfl[8] | wfl[9] | wfl[10] | wfl[11] | wfl[12]
                    | wfl[13] | wfl[14] | wfl[15];

    if (fb_any) {
        // ---- Fallback (pathological masks only): LOCAL full rebuild of both
        // images' 256-row masks (no inter-block traffic), then exact full-range
        // col_min for unconverged threads with fg-any gating.
        __syncthreads();              // all waves done reading wfl / fast-path lmask
        unsigned any0 = 0u, any1 = 0u;
        #pragma unroll 4
        for (int i = w; i < 512; i += 16) {   // 32 rows/wave
            int img = i >> 8, y = i & 255;
            const float* rowp = (img ? tgt : pred) + (b * HH + y) * WW;
            unsigned v;
            PACK_ROW(rowp, v);
            if (img) any1 |= v; else any0 |= v;
            if ((lane & 7) == 0) lmask[img][y][lane >> 3] = v;
        }
        unsigned long long A0 = __ballot(any0 != 0u);
        unsigned long long A1 = __ballot(any1 != 0u);
        if (lane == 0) wfl[w] = (A0 ? 1u : 0u) | (A1 ? 2u : 0u);
        __syncthreads();
        unsigned m = wfl[0] | wfl[1] | wfl[2] | wfl[3] | wfl[4] | wfl[5] | wfl[6]
                   | wfl[7] | wfl[8] | wfl[9] | wfl[10] | wfl[11] | wfl[12]
                   | wfl[13] | wfl[14] | wfl[15];
        unsigned fl_p = m & 1u, fl_t = m & 2u;
        if (!conv_p) {
            d2p = 0.0f;
            if (fl_p) {
                float best = col_min(&lmask[0][0][0], yq, x, ivp);
                float dt = sqrtf(fminf(best, BIGF));
                d2p = dt * dt;
            }
        }
        if (!conv_t) {
            d2t = 0.0f;
            if (fl_t) {
                float best = col_min(&lmask[1][0][0], yq, x, ivt);
                float dt = sqrtf(fminf(best, BIGF));
                d2t = dt * dt;
            }
        }
        // redo the block reduce with corrected values
        float ls = errsq * (d2p + d2t);
        #pragma unroll
        for (int off = 32; off > 0; off >>= 1)
            ls += __shfl_down(ls, off, 64);
        if (lane == 0) wsum[w] = ls;
        __syncthreads();
    }

    // ---- Ticket tail: publish partial (ACKed), then ticket; last finisher
    // reduces. Ordering: every block's accb store is ACKed at the coherence
    // point BEFORE its ticket add, so ticket 255 implies all 256 visible.
    if (tid == 0) {
        float s2 = 0.0f;
        #pragma unroll
        for (int i = 0; i < 16; ++i) s2 += wsum[i];
        STORE_RLX(&accb[blk], (unsigned long long)__double_as_longlong((double)s2));
        asm volatile("s_waitcnt vmcnt(0)" ::: "memory");  // partial ACKed pre-ticket
        while (LOAD_RLX(initf) != MAGIC)                  // one-shot: raised at entry
            __builtin_amdgcn_s_sleep(1);
        unsigned t = atomicAdd(cnt, 1u);                  // device-scope RMW
        lastFlag = (t == GRID - 1) ? 1u : 0u;
    }
    __syncthreads();
    if (lastFlag) {
        // this block drew the last ticket: all partials are at the coherence
        // point. 256 threads load one each, wave-reduce, write out.
        double v = 0.0;
        if (tid < GRID)
            v = __longlong_as_double((long long)LOAD_RLX(&accb[tid]));
        #pragma unroll
        for (int off = 32; off > 0; off >>= 1)
            v += __shfl_down(v, off, 64);
        if (tid < GRID && (tid & 63) == 0) dsum[tid >> 6] = v;
        __syncthreads();
        if (tid == 0)
            out[0] = (float)((dsum[0] + dsum[1] + dsum[2] + dsum[3])
                             * (1.0 / (double)NPIX));
    }
}

extern "C" void kernel_launch(void* const* d_in, const int* in_sizes, int n_in,
                              void* d_out, int out_size, void* d_ws, size_t ws_size,
                              hipStream_t stream) {
    const float* pred = (const float*)d_in[0];
    const float* tgt = (const float*)d_in[1];
    float* out = (float*)d_out;
    char* ws = (char*)d_ws;
    unsigned long long* accb = (unsigned long long*)(ws + WS_ACCB_OFF);
    unsigned* cnt = (unsigned*)(ws + WS_CNT_OFF);
    unsigned* initf = (unsigned*)(ws + WS_INIT_OFF);

    hdt_kernel<<<GRID, 1024, 0, stream>>>(pred, tgt, cnt, initf, accb, out);
}

// Round 11
// 59.574 us; speedup vs baseline: 1.1004x; 1.1004x over previous
//
#include <hip/hip_runtime.h>

#define BIGF 1e10f
#define HH 256
#define WW 256
#define BB 4
#define NPIX (BB * HH * WW)
#define GRID 256            // == #CUs: 1 block/CU
#define MAGIC 0x5F3A9C71u   // multi-byte value: cannot alias a byte-pattern ws poison
#define SMAX 3              // local column window; exact iff best <= (SMAX+1)^2
#define CONV_T 16.0f        // (SMAX+1)^2

// ws layout (bytes):
//   [0 .. 2047]     u64 accb[256] : per-block double partial sums (bit pattern)
//   [3072 .. 4095]  u32 done[256] : partial-sum-published flags
// NO workspace init needed: accb is read only after done==MAGIC.
#define WS_ACCB_OFF 0
#define WS_DONE_OFF 3072

#define LOAD_RLX(p)     __hip_atomic_load((p), __ATOMIC_RELAXED, __HIP_MEMORY_SCOPE_AGENT)
#define STORE_RLX(p, v) __hip_atomic_store((p), (v), __ATOMIC_RELAXED, __HIP_MEMORY_SCOPE_AGENT)

// Exact 1D distance^2 along a row to the nearest bit of class (mask ^ iv),
// from position x. 8 u32 words per row in LDS; near-uniform addresses per wave.
__device__ inline float row_d2(const unsigned* __restrict__ rm, int x, unsigned iv) {
    int wx = x >> 5, bx = x & 31;
    int dl = 1 << 20, dr = 1 << 20;
    unsigned m0 = rm[wx] ^ iv;                    // shared by both directions
    unsigned t = m0 & (0xFFFFFFFFu >> (31 - bx)); // bits <= bx
    int w = wx;
    while (true) {
        if (t) { int p = (w << 5) + 31 - __builtin_clz(t); dl = x - p; break; }
        if (--w < 0) break;
        t = rm[w] ^ iv;
    }
    t = m0 & (0xFFFFFFFFu << bx);                 // bits >= bx
    w = wx;
    while (true) {
        if (t) { int p = (w << 5) + __builtin_ctz(t); dr = p - x; break; }
        if (++w > 7) break;
        t = rm[w] ^ iv;
    }
    int d = dl < dr ? dl : dr;
    return (d > 255) ? BIGF : (float)(d * d);
}

// Exact expanding-window min-plus along the column (full range, fallback path).
__device__ inline float col_min(const unsigned* __restrict__ mb, int y, int x, unsigned iv) {
    float best = row_d2(mb + y * 8, x, iv);
    #pragma unroll 1
    for (int s = 1; s < HH; ++s) {
        float ss = (float)(s * s);
        if (ss >= best) break;
        int ym = y - s, yp = y + s;
        if (ym >= 0) best = fminf(best, row_d2(mb + ym * 8, x, iv) + ss);
        if (yp < HH) best = fminf(best, row_d2(mb + yp * 8, x, iv) + ss);
    }
    return best;
}

// Fused truncated variant: both images in ONE s-loop (2x ILP on the dependent
// LDS-scan chain). Per-image iterations are identical to the full loop while
// s <= SMAX; result exact iff it converged (best <= (SMAX+1)^2: any s>SMAX
// candidate costs >= that, and the full loop breaks on ss >= best).
__device__ inline void col_min2_win(const unsigned* __restrict__ mb0,
                                    const unsigned* __restrict__ mb1,
                                    int y, int x, unsigned iv0, unsigned iv1,
                                    float& b0, float& b1) {
    b0 = row_d2(mb0 + y * 8, x, iv0);
    b1 = row_d2(mb1 + y * 8, x, iv1);
    #pragma unroll 1
    for (int s = 1; s <= SMAX; ++s) {
        float ss = (float)(s * s);
        bool d0 = (ss >= b0), d1 = (ss >= b1);
        if (d0 && d1) break;
        int ym = y - s, yp = y + s;
        if (!d0) {
            if (ym >= 0) b0 = fminf(b0, row_d2(mb0 + ym * 8, x, iv0) + ss);
            if (yp < HH) b0 = fminf(b0, row_d2(mb0 + yp * 8, x, iv0) + ss);
        }
        if (!d1) {
            if (ym >= 0) b1 = fminf(b1, row_d2(mb1 + ym * 8, x, iv1) + ss);
            if (yp < HH) b1 = fminf(b1, row_d2(mb1 + yp * 8, x, iv1) + ss);
        }
    }
}

// pack one row's 256 pixels into 8 mask words: float4/lane + nibble + shfl OR-tree
#define PACK_ROW(rowp, vout)                                                  \
    {                                                                         \
        const float4 f = ((const float4*)(rowp))[lane];                       \
        unsigned nib = (f.x > 0.5f ? 1u : 0u) | (f.y > 0.5f ? 2u : 0u)        \
                     | (f.z > 0.5f ? 4u : 0u) | (f.w > 0.5f ? 8u : 0u);       \
        vout = nib << ((lane & 7) << 2);                                      \
        vout |= __shfl_xor(vout, 1, 64);                                      \
        vout |= __shfl_xor(vout, 2, 64);                                      \
        vout |= __shfl_xor(vout, 4, 64);                                      \
    }

// r9 structure (measured best) + r10's benign micro-cuts only.
// Fast path: local +-SMAX window build + fused truncated col_min (exact when
// converged; convergence implies fg-any), ONE barrier for ballot+reduce.
// Rare fallback: local FULL 512-row rebuild + exact col_min with fg-any gates.
// Tail: atomic-free store+flag, block 0 polls+reduces (NO same-address RMW
// chain -- r10 measured it at +6 us). XCD-chunked tile map.
__launch_bounds__(1024, 4)
__global__ void hdt_kernel(const float* __restrict__ pred,
                           const float* __restrict__ tgt,
                           unsigned* __restrict__ done,
                           unsigned long long* __restrict__ accb,
                           float* __restrict__ out) {
    // XCD-aware swizzle: blockIdx round-robins XCDs; chunk so logical tiles
    // 0..31 land on XCD0, etc. Speed-only (L2 locality), not correctness.
    int blk = ((blockIdx.x & 7) << 5) | (blockIdx.x >> 3);
    int b = blk >> 6;
    int tid = threadIdx.x;
    int w = tid >> 6, lane = tid & 63;

    __shared__ __align__(16) unsigned lmask[2][HH][8];   // 16 KB (full, for fallback)
    __shared__ unsigned wfl[16];
    __shared__ float wsum[16];
    __shared__ double dsum[4];

    // prefetch this thread's query pixels: latency hides under the build
    int x = tid & (WW - 1);
    int y0 = (blk & 63) << 2;
    int yq = y0 + (tid >> 8);                 // wave-uniform row of the 4-row tile
    int idx = (b * HH + yq) * WW + x;
    float pv = pred[idx], tv = tgt[idx];

    // ---- Local window build: rows [y0-SMAX, y0+3+SMAX] clamped, both images.
    // <= 20 row-builds: waves 0-3 do 2, waves 4-15 do 1.
    int ylo = y0 - SMAX; if (ylo < 0) ylo = 0;
    int yhi = y0 + 3 + SMAX; if (yhi > HH - 1) yhi = HH - 1;
    int nrows = yhi - ylo + 1;
    int tot = nrows * 2;
    #pragma unroll 2
    for (int i = w; i < tot; i += 16) {
        int img = (i >= nrows) ? 1 : 0;
        int y = ylo + (img ? i - nrows : i);
        const float* rowp = (img ? tgt : pred) + (b * HH + y) * WW;
        unsigned v;
        PACK_ROW(rowp, v);
        if ((lane & 7) == 0) lmask[img][y][lane >> 3] = v;
    }
    __syncthreads();

    // ---- Fast path: fused truncated col_min on the local window.
    unsigned ivp = (pv > 0.5f) ? 0xFFFFFFFFu : 0u;
    unsigned ivt = (tv > 0.5f) ? 0xFFFFFFFFu : 0u;
    float bp, bt;
    col_min2_win(&lmask[0][0][0], &lmask[1][0][0], yq, x, ivp, ivt, bp, bt);
    bool conv_p = (bp <= CONV_T), conv_t = (bt <= CONV_T);
    float d2p = 0.0f, d2t = 0.0f;
    // converged => bp,bt <= 16 << BIGF: fminf elided; sqrt->square kept to
    // match the reference's f32 rounding exactly.
    if (conv_p) { float dt = sqrtf(bp); d2p = dt * dt; }
    if (conv_t) { float dt = sqrtf(bt); d2t = dt * dt; }

    float e = pv - tv;
    float errsq = e * e;
    float lsum = errsq * (d2p + d2t);

    // ---- Single-barrier ballot + reduce: wave64 shuffle reduce, then wsum[w]
    // and the fallback flag wfl[w] published in the same LDS round trip.
    unsigned long long fb = __ballot(!(conv_p && conv_t));
    #pragma unroll
    for (int off = 32; off > 0; off >>= 1)
        lsum += __shfl_down(lsum, off, 64);
    if (lane == 0) { wsum[w] = lsum; wfl[w] = (fb != 0ULL) ? 1u : 0u; }
    __syncthreads();
    unsigned fb_any = wfl[0] | wfl[1] | wfl[2] | wfl[3] | wfl[4] | wfl[5] | wfl[6]
                    | wfl[7] | wfl[8] | wfl[9] | wfl[10] | wfl[11] | wfl[12]
                    | wfl[13] | wfl[14] | wfl[15];

    if (fb_any) {
        // ---- Fallback (pathological masks only): LOCAL full rebuild of both
        // images' 256-row masks (no inter-block traffic), then exact full-range
        // col_min for unconverged threads with fg-any gating.
        __syncthreads();              // all waves done reading wfl / fast-path lmask
        unsigned any0 = 0u, any1 = 0u;
        #pragma unroll 4
        for (int i = w; i < 512; i += 16) {   // 32 rows/wave
            int img = i >> 8, y = i & 255;
            const float* rowp = (img ? tgt : pred) + (b * HH + y) * WW;
            unsigned v;
            PACK_ROW(rowp, v);
            if (img) any1 |= v; else any0 |= v;
            if ((lane & 7) == 0) lmask[img][y][lane >> 3] = v;
        }
        unsigned long long A0 = __ballot(any0 != 0u);
        unsigned long long A1 = __ballot(any1 != 0u);
        if (lane == 0) wfl[w] = (A0 ? 1u : 0u) | (A1 ? 2u : 0u);
        __syncthreads();
        unsigned m = wfl[0] | wfl[1] | wfl[2] | wfl[3] | wfl[4] | wfl[5] | wfl[6]
                   | wfl[7] | wfl[8] | wfl[9] | wfl[10] | wfl[11] | wfl[12]
                   | wfl[13] | wfl[14] | wfl[15];
        unsigned fl_p = m & 1u, fl_t = m & 2u;
        if (!conv_p) {
            d2p = 0.0f;
            if (fl_p) {
                float best = col_min(&lmask[0][0][0], yq, x, ivp);
                float dt = sqrtf(fminf(best, BIGF));
                d2p = dt * dt;
            }
        }
        if (!conv_t) {
            d2t = 0.0f;
            if (fl_t) {
                float best = col_min(&lmask[1][0][0], yq, x, ivt);
                float dt = sqrtf(fminf(best, BIGF));
                d2t = dt * dt;
            }
        }
        // redo the block reduce with corrected values
        float ls = errsq * (d2p + d2t);
        #pragma unroll
        for (int off = 32; off > 0; off >>= 1)
            ls += __shfl_down(ls, off, 64);
        if (lane == 0) wsum[w] = ls;
        __syncthreads();
    }

    // ---- Atomic-free tail: publish partial, then block 0 reduces all 256.
    if (tid == 0) {
        float s2 = 0.0f;
        #pragma unroll
        for (int i = 0; i < 16; ++i) s2 += wsum[i];
        STORE_RLX(&accb[blk], (unsigned long long)__double_as_longlong((double)s2));
        asm volatile("s_waitcnt vmcnt(0)" ::: "memory");  // partial ACKed before flag
        STORE_RLX(&done[blk], MAGIC);
    }
    if (blk == 0) {   // waits only on others' COMPLETED work; nobody waits on blk 0
        double v = 0.0;
        if (tid < GRID) {
            while (LOAD_RLX(&done[tid]) != MAGIC)
                __builtin_amdgcn_s_sleep(1);
            v = __longlong_as_double((long long)LOAD_RLX(&accb[tid]));
        }
        #pragma unroll
        for (int off = 32; off > 0; off >>= 1)
            v += __shfl_down(v, off, 64);
        if (tid < GRID && (tid & 63) == 0) dsum[tid >> 6] = v;
        __syncthreads();
        if (tid == 0)
            out[0] = (float)((dsum[0] + dsum[1] + dsum[2] + dsum[3])
                             * (1.0 / (double)NPIX));
    }
}

extern "C" void kernel_launch(void* const* d_in, const int* in_sizes, int n_in,
                              void* d_out, int out_size, void* d_ws, size_t ws_size,
                              hipStream_t stream) {
    const float* pred = (const float*)d_in[0];
    const float* tgt = (const float*)d_in[1];
    float* out = (float*)d_out;
    char* ws = (char*)d_ws;
    unsigned long long* accb = (unsigned long long*)(ws + WS_ACCB_OFF);
    unsigned* done = (unsigned*)(ws + WS_DONE_OFF);

    hdt_kernel<<<GRID, 1024, 0, stream>>>(pred, tgt, done, accb, out);
}